// Round 5
// baseline (255.887 us; speedup 1.0000x reference)
//
#include <hip/hip_runtime.h>
#include <hip/hip_bf16.h>
#include <math.h>

// CVFusionProposalRefiner on MI355X — round 5.
// Pipeline:
//   1) k_misc:   [blocks 0..2048)   transpose fm -> fmT bf16 (d_out), bf16-in-LDS (17.9KB)
//                [2048..2817)       prep ABt/W2t bf16 + u/v fp32 (ws), 4 acc chains
//   2) k_gather: proj (fp32, 16-lane butterfly) + masked bf16 q-half + branchless
//                bilinear bf16 gather -> qraw, cov.  4 queries/wave, XCD<->batch.
//   3) k_gemm_fused: h = relu(qraw@ABt^T + m*u + cov*v + b1) -> LDS (bf16, swizzled)
//                    out = h@W2t^T + b2 -> fp32 d_out

#define NQ 65536
#define OFFSET_SCALE 0.05f

typedef __bf16 bf16x8 __attribute__((ext_vector_type(8)));
typedef float f32x4 __attribute__((ext_vector_type(4)));
typedef float f32x2 __attribute__((ext_vector_type(2)));

__device__ __forceinline__ float dot4(float4 a, float4 b) {
  return a.x * b.x + a.y * b.y + a.z * b.z + a.w * b.w;
}

__device__ __forceinline__ ushort f2bf(float f) {
  union { float f; unsigned u; } v; v.f = f;
  unsigned r = v.u + 0x7FFFu + ((v.u >> 16) & 1u);   // RNE
  return (ushort)(r >> 16);
}

__device__ __forceinline__ f32x2 up2(unsigned u) {
  union { unsigned u; float f; } lo, hi;
  lo.u = u << 16;
  hi.u = u & 0xFFFF0000u;
  f32x2 r = {lo.f, hi.f};
  return r;
}

__device__ __forceinline__ unsigned pkbf(f32x2 v) {
  float2 f; f.x = v[0]; f.y = v[1];
  union { __hip_bfloat162 h; unsigned u; } x;
  x.h = __float22bfloat162_rn(f);
  return x.u;
}

__device__ __forceinline__ void gload16(const void* g, void* s) {
  __builtin_amdgcn_global_load_lds(
      (const __attribute__((address_space(1))) void*)g,
      (__attribute__((address_space(3))) void*)s, 16, 0, 0);
}

// ---------------- 1) misc: transpose | prep --------------------------------
__global__ void __launch_bounds__(256) k_misc(
    const float* __restrict__ fm, ushort* __restrict__ fmT,
    const float* __restrict__ Wq, const float* __restrict__ Wf,
    const float* __restrict__ W1, const float* __restrict__ W2,
    const float* __restrict__ bq, const float* __restrict__ bf,
    ushort* __restrict__ ABt, ushort* __restrict__ W2t,
    float* __restrict__ uvec, float* __restrict__ vvec) {
  __shared__ ushort tile[128][70];    // 17920 B; stride 70 => <=2-way bank aliasing
  const int bid = blockIdx.x;
  const int t = threadIdx.x;

  if (bid < 2048) {                       // ---- transpose (bf16 in LDS) ----
    const int c0 = (bid & 3) * 64;
    const int y  = (bid >> 2) & 127;
    const int b  = bid >> 9;
#pragma unroll
    for (int rep = 0; rep < 32; ++rep) {
      const int idx = t + rep * 256;
      const int ci = idx >> 7, x = idx & 127;
      tile[x][ci] = f2bf(fm[(((size_t)(b * 256 + c0 + ci) * 128 + y) << 7) + x]);
    }
    __syncthreads();
#pragma unroll
    for (int rep = 0; rep < 8; ++rep) {
      const int idx = t + rep * 256;
      const int x = idx >> 4, cg = idx & 15;
      const ushort4 o = *(const ushort4*)&tile[x][cg * 4];
      *(ushort4*)(fmT + (((size_t)((b * 128 + y) * 128 + x)) << 8) + c0 + cg * 4) = o;
    }
  } else {                                // ---- prep ----
    const int blk = bid - 2048;
    const int n = t;
    if (blk < 256) {
      float s0 = 0.f, s1 = 0.f, s2 = 0.f, s3 = 0.f;
#pragma unroll 4
      for (int j = 0; j < 256; j += 4) {
        s0 = fmaf(Wq[blk * 256 + j + 0], W1[(j + 0) * 256 + n], s0);
        s1 = fmaf(Wq[blk * 256 + j + 1], W1[(j + 1) * 256 + n], s1);
        s2 = fmaf(Wq[blk * 256 + j + 2], W1[(j + 2) * 256 + n], s2);
        s3 = fmaf(Wq[blk * 256 + j + 3], W1[(j + 3) * 256 + n], s3);
      }
      ABt[(size_t)n * 512 + blk] = f2bf((s0 + s1) + (s2 + s3));
    } else if (blk < 512) {
      const int k = blk - 256;
      float s0 = 0.f, s1 = 0.f, s2 = 0.f, s3 = 0.f;
#pragma unroll 4
      for (int j = 0; j < 256; j += 4) {
        s0 = fmaf(Wf[k * 256 + j + 0], W1[(256 + j + 0) * 256 + n], s0);
        s1 = fmaf(Wf[k * 256 + j + 1], W1[(256 + j + 1) * 256 + n], s1);
        s2 = fmaf(Wf[k * 256 + j + 2], W1[(256 + j + 2) * 256 + n], s2);
        s3 = fmaf(Wf[k * 256 + j + 3], W1[(256 + j + 3) * 256 + n], s3);
      }
      ABt[(size_t)n * 512 + 256 + k] = f2bf((s0 + s1) + (s2 + s3));
    } else if (blk == 512) {
      float su = 0.f, sv = 0.f;
#pragma unroll 4
      for (int j = 0; j < 256; ++j) {
        su = fmaf(bq[j], W1[j * 256 + n], su);
        sv = fmaf(bf[j], W1[(256 + j) * 256 + n], sv);
      }
      uvec[n] = su;
      vvec[n] = sv;
    } else {
      const int k = blk - 513;
      W2t[(size_t)n * 256 + k] = f2bf(W2[(size_t)k * 256 + n]);
    }
  }
}

// ---------------- 2) gather: fused proj + branchless bilinear gather -------
__global__ void __launch_bounds__(256) k_gather(
    const float* __restrict__ queries, const float* __restrict__ ref,
    const int* __restrict__ valid, const float* __restrict__ Wo,
    const float* __restrict__ bo, const float* __restrict__ Ww,
    const float* __restrict__ bw, const ushort* __restrict__ fmT,
    ushort* __restrict__ qraw, float* __restrict__ cov) {
  __shared__ float sW[12][260];
  __shared__ float sb[12];
  const int t = threadIdx.x;
  for (int i = t; i < 2048; i += 256) sW[i & 7][i >> 3] = Wo[i];
  for (int i = t; i < 1024; i += 256) sW[8 + (i & 3)][i >> 2] = Ww[i];
  if (t < 8) sb[t] = bo[t];
  else if (t < 12) sb[t] = bw[t - 8];
  __syncthreads();

  const int lane = t & 63, wv = t >> 6;
  const int qs = lane >> 4;            // query slot within wave
  const int kc = lane & 15;            // channel group
  const int xcd = blockIdx.x & 7;
  const int b = xcd >> 1;
  const int p = ((blockIdx.x >> 3) << 1) | (xcd & 1);   // 0..511 within batch
  const ushort* fmTb = fmT + ((size_t)b << 22);

#pragma unroll 1
  for (int it = 0; it < 2; ++it) {
    const int qi = b * 16384 + it * 8192 + p * 16 + wv * 4 + qs;
    const float mf = (valid[qi] != 0) ? 1.0f : 0.0f;

    // ---- proj: 12 projections, 16-lane butterfly reduce ----
    float4 qv[4];
#pragma unroll
    for (int i = 0; i < 4; ++i)
      qv[i] = *(const float4*)(queries + (size_t)qi * 256 + kc * 4 + i * 64);
    // masked bf16 q-half while q is in registers
#pragma unroll
    for (int i = 0; i < 4; ++i) {
      ushort4 h;
      h.x = f2bf(qv[i].x * mf); h.y = f2bf(qv[i].y * mf);
      h.z = f2bf(qv[i].z * mf); h.w = f2bf(qv[i].w * mf);
      *(ushort4*)(qraw + (size_t)qi * 512 + kc * 4 + i * 64) = h;
    }
    float pr[12];
#pragma unroll
    for (int j = 0; j < 12; ++j) {
      float s = 0.f;
#pragma unroll
      for (int i = 0; i < 4; ++i)
        s += dot4(qv[i], *(const float4*)&sW[j][kc * 4 + i * 64]);
      pr[j] = s;
    }
#pragma unroll
    for (int m = 1; m < 16; m <<= 1) {
#pragma unroll
      for (int j = 0; j < 12; ++j) pr[j] += __shfl_xor(pr[j], m, 64);
    }

    // ---- offsets + softmax (uniform within 16-lane group) ----
    float o[8];
#pragma unroll
    for (int j = 0; j < 8; ++j) {
      const float x = pr[j] + sb[j];
      const float e = __expf(2.0f * fabsf(x));
      const float th = 1.0f - 2.0f * __builtin_amdgcn_rcpf(e + 1.0f);
      o[j] = copysignf(th, x) * OFFSET_SCALE;
    }
    float wl[4];
#pragma unroll
    for (int j = 0; j < 4; ++j) wl[j] = pr[8 + j] + sb[8 + j];
    const float wmax = fmaxf(fmaxf(wl[0], wl[1]), fmaxf(wl[2], wl[3]));
    float wsum = 0.f;
#pragma unroll
    for (int j = 0; j < 4; ++j) { wl[j] = __expf(wl[j] - wmax); wsum += wl[j]; }
    const float winv = mf * __builtin_amdgcn_rcpf(wsum);
    const float rx = ref[qi * 2], ry = ref[qi * 2 + 1];

    f32x2 acc[8] = {};
    float cv = 0.f;

#define CORN(PIXPTR, CF)                                                     \
    do {                                                                     \
      const float cfv = (CF);                                                \
      const uint4 u0 = *(const uint4*)((PIXPTR) + kc * 8);                   \
      const uint4 u1 = *(const uint4*)((PIXPTR) + kc * 8 + 128);             \
      const f32x2 c2 = {cfv, cfv};                                           \
      acc[0] += c2 * up2(u0.x); acc[1] += c2 * up2(u0.y);                    \
      acc[2] += c2 * up2(u0.z); acc[3] += c2 * up2(u0.w);                    \
      acc[4] += c2 * up2(u1.x); acc[5] += c2 * up2(u1.y);                    \
      acc[6] += c2 * up2(u1.z); acc[7] += c2 * up2(u1.w);                    \
    } while (0)

#pragma unroll
    for (int s = 0; s < 4; ++s) {
      const float wgt = wl[s] * winv;
      const float gx = fminf(fmaxf(rx + o[2 * s],     -1.2f), 1.2f);
      const float gy = fminf(fmaxf(ry + o[2 * s + 1], -1.2f), 1.2f);
      const float xf = (gx + 1.0f) * 63.5f;
      const float yf = (gy + 1.0f) * 63.5f;
      const float x0f = floorf(xf), y0f = floorf(yf);
      const float wx = xf - x0f, wy = yf - y0f;
      const int x0 = (int)x0f, y0 = (int)y0f;
      const float wx0 = ((unsigned)x0 < 128u) ? (1.0f - wx) : 0.0f;
      const float wx1 = ((unsigned)(x0 + 1) < 128u) ? wx : 0.0f;
      const float wy0 = ((unsigned)y0 < 128u) ? (wgt * (1.0f - wy)) : 0.0f;
      const float wy1 = ((unsigned)(y0 + 1) < 128u) ? (wgt * wy) : 0.0f;
      const int xc0 = min(max(x0, 0), 127), xc1 = min(max(x0 + 1, 0), 127);
      const int yc0 = min(max(y0, 0), 127), yc1 = min(max(y0 + 1, 0), 127);
      cv += (wx0 + wx1) * (wy0 + wy1);
      const ushort* r0 = fmTb + ((size_t)yc0 << 15);
      const ushort* r1 = fmTb + ((size_t)yc1 << 15);
      CORN(r0 + (xc0 << 8), wy0 * wx0);
      CORN(r0 + (xc1 << 8), wy0 * wx1);
      CORN(r1 + (xc0 << 8), wy1 * wx0);
      CORN(r1 + (xc1 << 8), wy1 * wx1);
    }
#undef CORN

    uint4 w0, w1;
    w0.x = pkbf(acc[0]); w0.y = pkbf(acc[1]); w0.z = pkbf(acc[2]); w0.w = pkbf(acc[3]);
    w1.x = pkbf(acc[4]); w1.y = pkbf(acc[5]); w1.z = pkbf(acc[6]); w1.w = pkbf(acc[7]);
    *(uint4*)(qraw + (size_t)qi * 512 + 256 + kc * 8) = w0;
    *(uint4*)(qraw + (size_t)qi * 512 + 256 + 128 + kc * 8) = w1;
    if (kc == 0) cov[qi] = cv;
  }
}

// ---------------- 3) fused GEMM1+GEMM2, M-tile 64, 4 waves -----------------
__global__ void __launch_bounds__(256, 3) k_gemm_fused(
    const ushort* __restrict__ qraw, const ushort* __restrict__ ABt,
    const ushort* __restrict__ W2t, const int* __restrict__ valid,
    const float* __restrict__ cov, const float* __restrict__ uvec,
    const float* __restrict__ vvec, const float* __restrict__ b1,
    const float* __restrict__ b2, float* __restrict__ out) {
  __shared__ ushort As[64 * 32];      // 4 KB
  __shared__ ushort Bs[256 * 32];     // 16 KB
  __shared__ ushort Hs[64 * 256];     // 32 KB, slot-XOR swizzled
  const int t = threadIdx.x;
  const int m0 = blockIdx.x * 64;
  const int wn = t >> 6, lane = t & 63;
  const int lr = lane & 15, lg = lane >> 4;

  const int srow = t >> 2;
  const int schunk = ((t & 3) ^ ((srow >> 1) & 3)) * 8;  // pre-swizzled source chunk
  const int swz = (lg ^ ((lr >> 1) & 3)) * 8;            // swizzled read offset

  const ushort* ag = qraw + (size_t)(m0 + srow) * 512 + schunk;
  const ushort* bg = ABt + (size_t)srow * 512 + schunk;
  ushort* la = As + t * 8;
  ushort* lb = Bs + t * 8;

  f32x4 acc[4][4] = {};

  // ---- phase 1: K = 512 ----
  for (int k0 = 0; k0 < 512; k0 += 32) {
    __syncthreads();
    gload16(ag + k0, la);
    gload16(bg + k0, lb);
    gload16(bg + 64 * 512 + k0, lb + 2048);
    gload16(bg + 128 * 512 + k0, lb + 4096);
    gload16(bg + 192 * 512 + k0, lb + 6144);
    __syncthreads();
    bf16x8 af[4], bfr[4];
#pragma unroll
    for (int m = 0; m < 4; ++m)
      af[m] = *(const bf16x8*)(As + (m * 16 + lr) * 32 + swz);
#pragma unroll
    for (int n = 0; n < 4; ++n)
      bfr[n] = *(const bf16x8*)(Bs + (wn * 64 + n * 16 + lr) * 32 + swz);
#pragma unroll
    for (int m = 0; m < 4; ++m)
#pragma unroll
      for (int n = 0; n < 4; ++n)
        acc[m][n] = __builtin_amdgcn_mfma_f32_16x16x32_bf16(af[m], bfr[n], acc[m][n], 0, 0, 0);
  }

  // ---- epilogue 1 -> Hs (bf16, swizzled) ----
  {
    float uu[4], vv[4], bb[4];
#pragma unroll
    for (int n = 0; n < 4; ++n) {
      const int col = wn * 64 + n * 16 + lr;
      uu[n] = uvec[col]; vv[n] = vvec[col]; bb[n] = b1[col];
    }
#pragma unroll
    for (int m = 0; m < 4; ++m)
#pragma unroll
      for (int j = 0; j < 4; ++j) {
        const int row = m * 16 + lg * 4 + j;      // local row
        const float mfv = valid[m0 + row] ? 1.0f : 0.0f;
        const float cvr = cov[m0 + row];
#pragma unroll
        for (int n = 0; n < 4; ++n) {
          const int col = wn * 64 + n * 16 + lr;
          float r = acc[m][n][j] + mfv * uu[n] + cvr * vv[n] + bb[n];
          r = fmaxf(r, 0.0f);
          const int slot = (col >> 3) ^ (row & 7);
          Hs[row * 256 + slot * 8 + (col & 7)] = f2bf(r);
        }
      }
  }

  // ---- phase 2: K = 256, A = Hs, B = W2t ----
  const ushort* cg = W2t + (size_t)srow * 256 + schunk;
#pragma unroll
  for (int m = 0; m < 4; ++m)
#pragma unroll
    for (int n = 0; n < 4; ++n) {
      f32x4 z = {0.f, 0.f, 0.f, 0.f};
      acc[m][n] = z;
    }

  for (int k0 = 0; k0 < 256; k0 += 32) {
    __syncthreads();
    gload16(cg + k0, lb);
    gload16(cg + 64 * 256 + k0, lb + 2048);
    gload16(cg + 128 * 256 + k0, lb + 4096);
    gload16(cg + 192 * 256 + k0, lb + 6144);
    __syncthreads();
    bf16x8 af[4], bfr[4];
#pragma unroll
    for (int m = 0; m < 4; ++m) {
      const int slot = ((k0 >> 3) + lg) ^ (lr & 7);
      af[m] = *(const bf16x8*)(Hs + (m * 16 + lr) * 256 + slot * 8);
    }
#pragma unroll
    for (int n = 0; n < 4; ++n)
      bfr[n] = *(const bf16x8*)(Bs + (wn * 64 + n * 16 + lr) * 32 + swz);
#pragma unroll
    for (int m = 0; m < 4; ++m)
#pragma unroll
      for (int n = 0; n < 4; ++n)
        acc[m][n] = __builtin_amdgcn_mfma_f32_16x16x32_bf16(af[m], bfr[n], acc[m][n], 0, 0, 0);
  }

  // ---- epilogue 2 -> out fp32 ----
  {
    float bb[4];
#pragma unroll
    for (int n = 0; n < 4; ++n) bb[n] = b2[wn * 64 + n * 16 + lr];
#pragma unroll
    for (int m = 0; m < 4; ++m)
#pragma unroll
      for (int j = 0; j < 4; ++j) {
        const int row = m0 + m * 16 + lg * 4 + j;
#pragma unroll
        for (int n = 0; n < 4; ++n)
          out[(size_t)row * 256 + wn * 64 + n * 16 + lr] = acc[m][n][j] + bb[n];
      }
  }
}

extern "C" void kernel_launch(void* const* d_in, const int* in_sizes, int n_in,
                              void* d_out, int out_size, void* d_ws, size_t ws_size,
                              hipStream_t stream) {
  const float* queries = (const float*)d_in[0];
  const float* ref     = (const float*)d_in[1];
  const float* fm      = (const float*)d_in[2];
  const int*   valid   = (const int*)d_in[3];
  const float* Wq = (const float*)d_in[4];
  const float* bq = (const float*)d_in[5];
  const float* Wf = (const float*)d_in[6];
  const float* bf = (const float*)d_in[7];
  const float* Wo = (const float*)d_in[8];
  const float* bo = (const float*)d_in[9];
  const float* Ww = (const float*)d_in[10];
  const float* bw = (const float*)d_in[11];
  const float* W1 = (const float*)d_in[12];
  const float* b1 = (const float*)d_in[13];
  const float* W2 = (const float*)d_in[14];
  const float* b2 = (const float*)d_in[15];
  float* out = (float*)d_out;

  // ws layout (bytes): qraw 67108864 | cov 262144 | ABt 262144 | W2t 131072 | u,v 2048
  char* ws = (char*)d_ws;
  ushort* qraw = (ushort*)ws;                         // [65536, 512] bf16
  float*  cov  = (float*)(ws + 67108864);             // [65536]
  ushort* ABt  = (ushort*)(ws + 67108864 + 262144);   // [256, 512] bf16
  ushort* W2t  = (ushort*)(ws + 67108864 + 524288);   // [256, 256] bf16
  float*  uvec = (float*)(ws + 67108864 + 655360);
  float*  vvec = uvec + 256;

  // d_out double-duty: fmT bf16 in floats [0 .. 8388608); overwritten by k_gemm_fused.
  ushort* fmT  = (ushort*)d_out;

  k_misc<<<2817, 256, 0, stream>>>(fm, fmT, Wq, Wf, W1, W2, bq, bf, ABt, W2t,
                                   uvec, vvec);
  k_gather<<<2048, 256, 0, stream>>>(queries, ref, valid, Wo, bo, Ww, bw, fmT,
                                     qraw, cov);
  k_gemm_fused<<<1024, 256, 0, stream>>>(qraw, ABt, W2t, valid, cov, uvec, vvec,
                                         b1, b2, out);
}

// Round 6
// 136.881 us; speedup vs baseline: 1.8694x; 1.8694x over previous
//
#include <hip/hip_runtime.h>
#include <hip/hip_bf16.h>
#include <math.h>

// CVFusionProposalRefiner on MI355X — round 6.
// Round-5 post-mortem: fusing proj into gather blew VGPR to 148 / occupancy to 11%
// (latency-bound gather needs TLP). Revert to round-4 structure, but with the
// round-5 bf16-in-LDS transpose so k_misc's LDS is 17.9KB (8 blocks/CU, was 4).
// Pipeline:
//   1) k_misc:   [0..2048)    transpose fm -> fmT bf16 (d_out), bf16-in-LDS
//                [2048..2817) prep ABt/W2t bf16 + u/v fp32 (ws)
//                [2817..6913) proj = q@[Wo|Ww]+b -> d_out tail + masked bf16 q -> qraw
//   2) k_gather: 4 queries/wave, branchless bilinear bf16 gather -> qraw[:,256:], cov
//   3) k_gemm_fused: h = relu(qraw@ABt^T + m*u + cov*v + b1) -> LDS (bf16, swizzled)
//                    out = h@W2t^T + b2 -> fp32 d_out

#define NQ 65536
#define OFFSET_SCALE 0.05f

typedef __bf16 bf16x8 __attribute__((ext_vector_type(8)));
typedef float f32x4 __attribute__((ext_vector_type(4)));
typedef float f32x2 __attribute__((ext_vector_type(2)));

__device__ __forceinline__ float dot4(float4 a, float4 b) {
  return a.x * b.x + a.y * b.y + a.z * b.z + a.w * b.w;
}

__device__ __forceinline__ ushort f2bf(float f) {
  union { float f; unsigned u; } v; v.f = f;
  unsigned r = v.u + 0x7FFFu + ((v.u >> 16) & 1u);   // RNE
  return (ushort)(r >> 16);
}

__device__ __forceinline__ f32x2 up2(unsigned u) {
  union { unsigned u; float f; } lo, hi;
  lo.u = u << 16;
  hi.u = u & 0xFFFF0000u;
  f32x2 r = {lo.f, hi.f};
  return r;
}

__device__ __forceinline__ unsigned pkbf(f32x2 v) {
  float2 f; f.x = v[0]; f.y = v[1];
  union { __hip_bfloat162 h; unsigned u; } x;
  x.h = __float22bfloat162_rn(f);
  return x.u;
}

__device__ __forceinline__ void gload16(const void* g, void* s) {
  __builtin_amdgcn_global_load_lds(
      (const __attribute__((address_space(1))) void*)g,
      (__attribute__((address_space(3))) void*)s, 16, 0, 0);
}

// ---------------- 1) misc: transpose | prep | proj -------------------------
__global__ void __launch_bounds__(256) k_misc(
    const float* __restrict__ fm, ushort* __restrict__ fmT,
    const float* __restrict__ Wq, const float* __restrict__ Wf,
    const float* __restrict__ W1, const float* __restrict__ W2,
    const float* __restrict__ bq, const float* __restrict__ bf,
    ushort* __restrict__ ABt, ushort* __restrict__ W2t,
    float* __restrict__ uvec, float* __restrict__ vvec,
    const float* __restrict__ queries, const int* __restrict__ valid,
    const float* __restrict__ Wo, const float* __restrict__ bo,
    const float* __restrict__ Ww, const float* __restrict__ bw,
    float* __restrict__ proj, ushort* __restrict__ qraw) {
  __shared__ ushort tile[128][70];    // 17920 B (proj section reuses as float space)
  const int bid = blockIdx.x;
  const int t = threadIdx.x;

  if (bid < 2048) {                       // ---- transpose (bf16 in LDS) ----
    const int c0 = (bid & 3) * 64;
    const int y  = (bid >> 2) & 127;
    const int b  = bid >> 9;
#pragma unroll
    for (int rep = 0; rep < 32; ++rep) {
      const int idx = t + rep * 256;
      const int ci = idx >> 7, x = idx & 127;
      tile[x][ci] = f2bf(fm[(((size_t)(b * 256 + c0 + ci) * 128 + y) << 7) + x]);
    }
    __syncthreads();
#pragma unroll
    for (int rep = 0; rep < 8; ++rep) {
      const int idx = t + rep * 256;
      const int x = idx >> 4, cg = idx & 15;
      const ushort4 o = *(const ushort4*)&tile[x][cg * 4];
      *(ushort4*)(fmT + (((size_t)((b * 128 + y) * 128 + x)) << 8) + c0 + cg * 4) = o;
    }
  } else if (bid < 2817) {                // ---- prep ----
    const int blk = bid - 2048;
    const int n = t;
    if (blk < 256) {
      float s0 = 0.f, s1 = 0.f, s2 = 0.f, s3 = 0.f;
#pragma unroll 4
      for (int j = 0; j < 256; j += 4) {
        s0 = fmaf(Wq[blk * 256 + j + 0], W1[(j + 0) * 256 + n], s0);
        s1 = fmaf(Wq[blk * 256 + j + 1], W1[(j + 1) * 256 + n], s1);
        s2 = fmaf(Wq[blk * 256 + j + 2], W1[(j + 2) * 256 + n], s2);
        s3 = fmaf(Wq[blk * 256 + j + 3], W1[(j + 3) * 256 + n], s3);
      }
      ABt[(size_t)n * 512 + blk] = f2bf((s0 + s1) + (s2 + s3));
    } else if (blk < 512) {
      const int k = blk - 256;
      float s0 = 0.f, s1 = 0.f, s2 = 0.f, s3 = 0.f;
#pragma unroll 4
      for (int j = 0; j < 256; j += 4) {
        s0 = fmaf(Wf[k * 256 + j + 0], W1[(256 + j + 0) * 256 + n], s0);
        s1 = fmaf(Wf[k * 256 + j + 1], W1[(256 + j + 1) * 256 + n], s1);
        s2 = fmaf(Wf[k * 256 + j + 2], W1[(256 + j + 2) * 256 + n], s2);
        s3 = fmaf(Wf[k * 256 + j + 3], W1[(256 + j + 3) * 256 + n], s3);
      }
      ABt[(size_t)n * 512 + 256 + k] = f2bf((s0 + s1) + (s2 + s3));
    } else if (blk == 512) {
      float su = 0.f, sv = 0.f;
      for (int j = 0; j < 256; ++j) {
        su = fmaf(bq[j], W1[j * 256 + n], su);
        sv = fmaf(bf[j], W1[(256 + j) * 256 + n], sv);
      }
      uvec[n] = su;
      vvec[n] = sv;
    } else {
      const int k = blk - 513;
      W2t[(size_t)n * 256 + k] = f2bf(W2[(size_t)k * 256 + n]);
    }
  } else {                                // ---- proj ----
    const int blk = bid - 2817;
    float (*sW)[260] = (float(*)[260])&tile[0][0];       // 12*260*4 = 12480 B
    float* sb = (float*)&tile[0][0] + 12 * 260;          // +48 B  (< 17920)
    for (int i = t; i < 2048; i += 256) sW[i & 7][i >> 3] = Wo[i];
    for (int i = t; i < 1024; i += 256) sW[8 + (i & 3)][i >> 2] = Ww[i];
    if (t < 8) sb[t] = bo[t];
    else if (t < 12) sb[t] = bw[t - 8];
    __syncthreads();

    const int lane = t & 63, wv = t >> 6;
    const int ql = lane >> 4, kc = lane & 15;
    const int qi = blk * 16 + wv * 4 + ql;
    const float mf = (valid[qi] != 0) ? 1.0f : 0.0f;

    float4 qv[4];
#pragma unroll
    for (int i = 0; i < 4; ++i)
      qv[i] = *(const float4*)(queries + (size_t)qi * 256 + kc * 4 + i * 64);

    float pr[12];
#pragma unroll
    for (int j = 0; j < 12; ++j) {
      float s = 0.f;
#pragma unroll
      for (int i = 0; i < 4; ++i)
        s += dot4(qv[i], *(const float4*)&sW[j][kc * 4 + i * 64]);
      pr[j] = s;
    }
#pragma unroll
    for (int m = 1; m < 16; m <<= 1) {
#pragma unroll
      for (int j = 0; j < 12; ++j) pr[j] += __shfl_xor(pr[j], m, 64);
    }
    if (kc == 0) {
      float4* pp = (float4*)(proj + (size_t)qi * 16);
      const float4 o0 = {pr[0] + sb[0], pr[1] + sb[1], pr[2] + sb[2],  pr[3] + sb[3]};
      const float4 o1 = {pr[4] + sb[4], pr[5] + sb[5], pr[6] + sb[6],  pr[7] + sb[7]};
      const float4 o2 = {pr[8] + sb[8], pr[9] + sb[9], pr[10] + sb[10], pr[11] + sb[11]};
      pp[0] = o0; pp[1] = o1; pp[2] = o2;
    }
#pragma unroll
    for (int i = 0; i < 4; ++i) {
      ushort4 h;
      h.x = f2bf(qv[i].x * mf); h.y = f2bf(qv[i].y * mf);
      h.z = f2bf(qv[i].z * mf); h.w = f2bf(qv[i].w * mf);
      *(ushort4*)(qraw + (size_t)qi * 512 + kc * 4 + i * 64) = h;
    }
  }
}

// ---------------- 2) gather: 4 queries/wave, branchless, packed ------------
__global__ void __launch_bounds__(256) k_gather(
    const float* __restrict__ proj, const float* __restrict__ ref,
    const int* __restrict__ valid, const ushort* __restrict__ fmT,
    ushort* __restrict__ qraw, float* __restrict__ cov) {
  const int t = threadIdx.x, lane = t & 63, wv = t >> 6;
  const int qs = lane >> 4;            // query slot within wave
  const int kc = lane & 15;            // channel group (8 ch per half)
  const int xcd = blockIdx.x & 7;
  const int b = xcd >> 1;
  const int p = ((blockIdx.x >> 3) << 1) | (xcd & 1);   // 0..511 within batch
  const ushort* fmTb = fmT + ((size_t)b << 22);

#pragma unroll 1
  for (int it = 0; it < 2; ++it) {
    const int qi = b * 16384 + it * 8192 + p * 16 + wv * 4 + qs;
    const float mf = (valid[qi] != 0) ? 1.0f : 0.0f;
    const float4 pA = *(const float4*)(proj + (size_t)qi * 16);
    const float4 pB = *(const float4*)(proj + (size_t)qi * 16 + 4);
    const float4 pC = *(const float4*)(proj + (size_t)qi * 16 + 8);
    const float rx = ref[qi * 2], ry = ref[qi * 2 + 1];

    const float po[8] = {pA.x, pA.y, pA.z, pA.w, pB.x, pB.y, pB.z, pB.w};
    float o[8];
#pragma unroll
    for (int j = 0; j < 8; ++j) {
      const float x = po[j];
      const float e = __expf(2.0f * fabsf(x));
      const float th = 1.0f - 2.0f * __builtin_amdgcn_rcpf(e + 1.0f);
      o[j] = copysignf(th, x) * OFFSET_SCALE;
    }
    float wl[4] = {pC.x, pC.y, pC.z, pC.w};
    const float wmax = fmaxf(fmaxf(wl[0], wl[1]), fmaxf(wl[2], wl[3]));
    float wsum = 0.f;
#pragma unroll
    for (int j = 0; j < 4; ++j) { wl[j] = __expf(wl[j] - wmax); wsum += wl[j]; }
    const float winv = mf * __builtin_amdgcn_rcpf(wsum);

    f32x2 acc[8] = {};
    float cv = 0.f;

#define CORN(PIXPTR, CF)                                                     \
    do {                                                                     \
      const float cfv = (CF);                                                \
      const uint4 u0 = *(const uint4*)((PIXPTR) + kc * 8);                   \
      const uint4 u1 = *(const uint4*)((PIXPTR) + kc * 8 + 128);             \
      const f32x2 c2 = {cfv, cfv};                                           \
      acc[0] += c2 * up2(u0.x); acc[1] += c2 * up2(u0.y);                    \
      acc[2] += c2 * up2(u0.z); acc[3] += c2 * up2(u0.w);                    \
      acc[4] += c2 * up2(u1.x); acc[5] += c2 * up2(u1.y);                    \
      acc[6] += c2 * up2(u1.z); acc[7] += c2 * up2(u1.w);                    \
    } while (0)

#pragma unroll
    for (int s = 0; s < 4; ++s) {
      const float wgt = wl[s] * winv;
      const float gx = fminf(fmaxf(rx + o[2 * s],     -1.2f), 1.2f);
      const float gy = fminf(fmaxf(ry + o[2 * s + 1], -1.2f), 1.2f);
      const float xf = (gx + 1.0f) * 63.5f;
      const float yf = (gy + 1.0f) * 63.5f;
      const float x0f = floorf(xf), y0f = floorf(yf);
      const float wx = xf - x0f, wy = yf - y0f;
      const int x0 = (int)x0f, y0 = (int)y0f;
      const float wx0 = ((unsigned)x0 < 128u) ? (1.0f - wx) : 0.0f;
      const float wx1 = ((unsigned)(x0 + 1) < 128u) ? wx : 0.0f;
      const float wy0 = ((unsigned)y0 < 128u) ? (wgt * (1.0f - wy)) : 0.0f;
      const float wy1 = ((unsigned)(y0 + 1) < 128u) ? (wgt * wy) : 0.0f;
      const int xc0 = min(max(x0, 0), 127), xc1 = min(max(x0 + 1, 0), 127);
      const int yc0 = min(max(y0, 0), 127), yc1 = min(max(y0 + 1, 0), 127);
      cv += (wx0 + wx1) * (wy0 + wy1);
      const ushort* r0 = fmTb + ((size_t)yc0 << 15);   // yc0*128*256
      const ushort* r1 = fmTb + ((size_t)yc1 << 15);
      CORN(r0 + (xc0 << 8), wy0 * wx0);
      CORN(r0 + (xc1 << 8), wy0 * wx1);
      CORN(r1 + (xc0 << 8), wy1 * wx0);
      CORN(r1 + (xc1 << 8), wy1 * wx1);
    }
#undef CORN

    uint4 w0, w1;
    w0.x = pkbf(acc[0]); w0.y = pkbf(acc[1]); w0.z = pkbf(acc[2]); w0.w = pkbf(acc[3]);
    w1.x = pkbf(acc[4]); w1.y = pkbf(acc[5]); w1.z = pkbf(acc[6]); w1.w = pkbf(acc[7]);
    *(uint4*)(qraw + (size_t)qi * 512 + 256 + kc * 8) = w0;
    *(uint4*)(qraw + (size_t)qi * 512 + 256 + 128 + kc * 8) = w1;
    if (kc == 0) cov[qi] = cv;
  }
}

// ---------------- 3) fused GEMM1+GEMM2, M-tile 64, 4 waves -----------------
__global__ void __launch_bounds__(256, 3) k_gemm_fused(
    const ushort* __restrict__ qraw, const ushort* __restrict__ ABt,
    const ushort* __restrict__ W2t, const int* __restrict__ valid,
    const float* __restrict__ cov, const float* __restrict__ uvec,
    const float* __restrict__ vvec, const float* __restrict__ b1,
    const float* __restrict__ b2, float* __restrict__ out) {
  __shared__ ushort As[64 * 32];      // 4 KB
  __shared__ ushort Bs[256 * 32];     // 16 KB
  __shared__ ushort Hs[64 * 256];     // 32 KB, slot-XOR swizzled
  const int t = threadIdx.x;
  const int m0 = blockIdx.x * 64;
  const int wn = t >> 6, lane = t & 63;
  const int lr = lane & 15, lg = lane >> 4;

  const int srow = t >> 2;
  const int schunk = ((t & 3) ^ ((srow >> 1) & 3)) * 8;  // pre-swizzled source chunk
  const int swz = (lg ^ ((lr >> 1) & 3)) * 8;            // swizzled read offset

  const ushort* ag = qraw + (size_t)(m0 + srow) * 512 + schunk;
  const ushort* bg = ABt + (size_t)srow * 512 + schunk;
  ushort* la = As + t * 8;
  ushort* lb = Bs + t * 8;

  f32x4 acc[4][4] = {};

  // ---- phase 1: K = 512 ----
  for (int k0 = 0; k0 < 512; k0 += 32) {
    __syncthreads();
    gload16(ag + k0, la);
    gload16(bg + k0, lb);
    gload16(bg + 64 * 512 + k0, lb + 2048);
    gload16(bg + 128 * 512 + k0, lb + 4096);
    gload16(bg + 192 * 512 + k0, lb + 6144);
    __syncthreads();
    bf16x8 af[4], bfr[4];
#pragma unroll
    for (int m = 0; m < 4; ++m)
      af[m] = *(const bf16x8*)(As + (m * 16 + lr) * 32 + swz);
#pragma unroll
    for (int n = 0; n < 4; ++n)
      bfr[n] = *(const bf16x8*)(Bs + (wn * 64 + n * 16 + lr) * 32 + swz);
#pragma unroll
    for (int m = 0; m < 4; ++m)
#pragma unroll
      for (int n = 0; n < 4; ++n)
        acc[m][n] = __builtin_amdgcn_mfma_f32_16x16x32_bf16(af[m], bfr[n], acc[m][n], 0, 0, 0);
  }

  // ---- epilogue 1 -> Hs (bf16, swizzled) ----
  {
    float uu[4], vv[4], bb[4];
#pragma unroll
    for (int n = 0; n < 4; ++n) {
      const int col = wn * 64 + n * 16 + lr;
      uu[n] = uvec[col]; vv[n] = vvec[col]; bb[n] = b1[col];
    }
#pragma unroll
    for (int m = 0; m < 4; ++m)
#pragma unroll
      for (int j = 0; j < 4; ++j) {
        const int row = m * 16 + lg * 4 + j;      // local row
        const float mfv = valid[m0 + row] ? 1.0f : 0.0f;
        const float cvr = cov[m0 + row];
#pragma unroll
        for (int n = 0; n < 4; ++n) {
          const int col = wn * 64 + n * 16 + lr;
          float r = acc[m][n][j] + mfv * uu[n] + cvr * vv[n] + bb[n];
          r = fmaxf(r, 0.0f);
          const int slot = (col >> 3) ^ (row & 7);
          Hs[row * 256 + slot * 8 + (col & 7)] = f2bf(r);
        }
      }
  }

  // ---- phase 2: K = 256, A = Hs, B = W2t ----
  const ushort* cg = W2t + (size_t)srow * 256 + schunk;
#pragma unroll
  for (int m = 0; m < 4; ++m)
#pragma unroll
    for (int n = 0; n < 4; ++n) {
      f32x4 z = {0.f, 0.f, 0.f, 0.f};
      acc[m][n] = z;
    }

  for (int k0 = 0; k0 < 256; k0 += 32) {
    __syncthreads();
    gload16(cg + k0, lb);
    gload16(cg + 64 * 256 + k0, lb + 2048);
    gload16(cg + 128 * 256 + k0, lb + 4096);
    gload16(cg + 192 * 256 + k0, lb + 6144);
    __syncthreads();
    bf16x8 af[4], bfr[4];
#pragma unroll
    for (int m = 0; m < 4; ++m) {
      const int slot = ((k0 >> 3) + lg) ^ (lr & 7);
      af[m] = *(const bf16x8*)(Hs + (m * 16 + lr) * 256 + slot * 8);
    }
#pragma unroll
    for (int n = 0; n < 4; ++n)
      bfr[n] = *(const bf16x8*)(Bs + (wn * 64 + n * 16 + lr) * 32 + swz);
#pragma unroll
    for (int m = 0; m < 4; ++m)
#pragma unroll
      for (int n = 0; n < 4; ++n)
        acc[m][n] = __builtin_amdgcn_mfma_f32_16x16x32_bf16(af[m], bfr[n], acc[m][n], 0, 0, 0);
  }

  // ---- epilogue 2 -> out fp32 ----
  {
    float bb[4];
#pragma unroll
    for (int n = 0; n < 4; ++n) bb[n] = b2[wn * 64 + n * 16 + lr];
#pragma unroll
    for (int m = 0; m < 4; ++m)
#pragma unroll
      for (int j = 0; j < 4; ++j) {
        const int row = m0 + m * 16 + lg * 4 + j;
#pragma unroll
        for (int n = 0; n < 4; ++n)
          out[(size_t)row * 256 + wn * 64 + n * 16 + lr] = acc[m][n][j] + bb[n];
      }
  }
}

extern "C" void kernel_launch(void* const* d_in, const int* in_sizes, int n_in,
                              void* d_out, int out_size, void* d_ws, size_t ws_size,
                              hipStream_t stream) {
  const float* queries = (const float*)d_in[0];
  const float* ref     = (const float*)d_in[1];
  const float* fm      = (const float*)d_in[2];
  const int*   valid   = (const int*)d_in[3];
  const float* Wq = (const float*)d_in[4];
  const float* bq = (const float*)d_in[5];
  const float* Wf = (const float*)d_in[6];
  const float* bf = (const float*)d_in[7];
  const float* Wo = (const float*)d_in[8];
  const float* bo = (const float*)d_in[9];
  const float* Ww = (const float*)d_in[10];
  const float* bw = (const float*)d_in[11];
  const float* W1 = (const float*)d_in[12];
  const float* b1 = (const float*)d_in[13];
  const float* W2 = (const float*)d_in[14];
  const float* b2 = (const float*)d_in[15];
  float* out = (float*)d_out;

  // ws layout (bytes): qraw 67108864 | cov 262144 | ABt 262144 | W2t 131072 | u,v 2048
  char* ws = (char*)d_ws;
  ushort* qraw = (ushort*)ws;                         // [65536, 512] bf16
  float*  cov  = (float*)(ws + 67108864);             // [65536]
  ushort* ABt  = (ushort*)(ws + 67108864 + 262144);   // [256, 512] bf16
  ushort* W2t  = (ushort*)(ws + 67108864 + 524288);   // [256, 256] bf16
  float*  uvec = (float*)(ws + 67108864 + 655360);
  float*  vvec = uvec + 256;

  // d_out multi-duty (all regions dead before k_gemm_fused writes out):
  //   floats [0 .. 8388608)        fmT bf16 (16.77M ushorts)
  //   floats [9437184 .. 10485760) proj [65536,16] f32
  ushort* fmT  = (ushort*)d_out;
  float*  proj = out + 9437184;

  k_misc<<<6913, 256, 0, stream>>>(fm, fmT, Wq, Wf, W1, W2, bq, bf, ABt, W2t,
                                   uvec, vvec, queries, valid, Wo, bo, Ww, bw,
                                   proj, qraw);
  k_gather<<<2048, 256, 0, stream>>>(proj, ref, valid, fmT, qraw, cov);
  k_gemm_fused<<<1024, 256, 0, stream>>>(qraw, ABt, W2t, valid, cov, uvec, vvec,
                                         b1, b2, out);
}

// Round 7
// 136.197 us; speedup vs baseline: 1.8788x; 1.0050x over previous
//
#include <hip/hip_runtime.h>
#include <hip/hip_bf16.h>
#include <math.h>

// CVFusionProposalRefiner on MI355X — round 7.
// Round-6 lesson: k_misc's sections are each latency-bound on DIFFERENT pipes
// and run back-to-back (block dispatch order). Fix: interleave transpose/proj
// blocks 1:2 so every CU holds a resource mix; consolidate prep 769->49 blocks
// (16 rows/block, uniform scalar source reads, no tail).
// Pipeline:
//   1) k_misc:   [0..49)   prep: ABt/W2t bf16 + u/v fp32 (ws)   [launched first]
//                [49..6193) interleaved: %3==0 transpose (2048), else proj (4096)
//   2) k_gather: 4 queries/wave, branchless bilinear bf16 gather -> qraw[:,256:], cov
//   3) k_gemm_fused: h = relu(qraw@ABt^T + m*u + cov*v + b1) -> LDS (bf16, swizzled)
//                    out = h@W2t^T + b2 -> fp32 d_out

#define NQ 65536
#define OFFSET_SCALE 0.05f

typedef __bf16 bf16x8 __attribute__((ext_vector_type(8)));
typedef float f32x4 __attribute__((ext_vector_type(4)));
typedef float f32x2 __attribute__((ext_vector_type(2)));
typedef unsigned short u16x8 __attribute__((ext_vector_type(8)));

__device__ __forceinline__ float dot4(float4 a, float4 b) {
  return a.x * b.x + a.y * b.y + a.z * b.z + a.w * b.w;
}

__device__ __forceinline__ ushort f2bf(float f) {
  union { float f; unsigned u; } v; v.f = f;
  unsigned r = v.u + 0x7FFFu + ((v.u >> 16) & 1u);   // RNE
  return (ushort)(r >> 16);
}

__device__ __forceinline__ f32x2 up2(unsigned u) {
  union { unsigned u; float f; } lo, hi;
  lo.u = u << 16;
  hi.u = u & 0xFFFF0000u;
  f32x2 r = {lo.f, hi.f};
  return r;
}

__device__ __forceinline__ unsigned pkbf(f32x2 v) {
  float2 f; f.x = v[0]; f.y = v[1];
  union { __hip_bfloat162 h; unsigned u; } x;
  x.h = __float22bfloat162_rn(f);
  return x.u;
}

__device__ __forceinline__ void gload16(const void* g, void* s) {
  __builtin_amdgcn_global_load_lds(
      (const __attribute__((address_space(1))) void*)g,
      (__attribute__((address_space(3))) void*)s, 16, 0, 0);
}

// ---------------- 1) misc: prep | interleaved transpose/proj ---------------
__global__ void __launch_bounds__(256) k_misc(
    const float* __restrict__ fm, ushort* __restrict__ fmT,
    const float* __restrict__ Wq, const float* __restrict__ Wf,
    const float* __restrict__ W1, const float* __restrict__ W2,
    const float* __restrict__ bq, const float* __restrict__ bf,
    ushort* __restrict__ ABt, ushort* __restrict__ W2t,
    float* __restrict__ uvec, float* __restrict__ vvec,
    const float* __restrict__ queries, const int* __restrict__ valid,
    const float* __restrict__ Wo, const float* __restrict__ bo,
    const float* __restrict__ Ww, const float* __restrict__ bw,
    float* __restrict__ proj, ushort* __restrict__ qraw) {
  __shared__ ushort tile[128][70];    // 17920 B (proj reuses as float space)
  const int bid = blockIdx.x;
  const int t = threadIdx.x;

  if (bid < 49) {                         // ---- prep (16 rows / block) ----
    const int n = t;
    if (bid < 32) {                       // ABt rows k0..k0+15
      const int k0 = bid * 16;
      const float* src = (bid < 16) ? (Wq + (size_t)k0 * 256)
                                    : (Wf + (size_t)(k0 - 256) * 256);
      const int joff = (bid < 16) ? 0 : 256;
      float acc[16];
#pragma unroll
      for (int r = 0; r < 16; ++r) acc[r] = 0.f;
#pragma unroll 4
      for (int j = 0; j < 256; ++j) {
        const float w = W1[(size_t)(j + joff) * 256 + n];
#pragma unroll
        for (int r = 0; r < 16; ++r) acc[r] = fmaf(src[r * 256 + j], w, acc[r]);
      }
      u16x8 o0, o1;
#pragma unroll
      for (int r = 0; r < 8; ++r) { o0[r] = f2bf(acc[r]); o1[r] = f2bf(acc[8 + r]); }
      *(u16x8*)(ABt + (size_t)n * 512 + k0) = o0;
      *(u16x8*)(ABt + (size_t)n * 512 + k0 + 8) = o1;
    } else if (bid == 32) {               // u = bq@W1a, v = bf@W1b
      float su = 0.f, sv = 0.f;
      for (int j = 0; j < 256; ++j) {
        su = fmaf(bq[j], W1[(size_t)j * 256 + n], su);
        sv = fmaf(bf[j], W1[(size_t)(256 + j) * 256 + n], sv);
      }
      uvec[n] = su;
      vvec[n] = sv;
    } else {                              // W2t rows k0..k0+15
      const int k0 = (bid - 33) * 16;
      u16x8 o0, o1;
#pragma unroll
      for (int r = 0; r < 8; ++r) {
        o0[r] = f2bf(W2[(size_t)(k0 + r) * 256 + n]);
        o1[r] = f2bf(W2[(size_t)(k0 + 8 + r) * 256 + n]);
      }
      *(u16x8*)(W2t + (size_t)n * 256 + k0) = o0;
      *(u16x8*)(W2t + (size_t)n * 256 + k0 + 8) = o1;
    }
    return;
  }

  const int r3 = bid - 49;
  if ((r3 % 3) == 0) {                    // ---- transpose (bf16 in LDS) ----
    const int tb = r3 / 3;                // 0..2047
    const int c0 = (tb & 3) * 64;
    const int y  = (tb >> 2) & 127;
    const int b  = tb >> 9;
#pragma unroll
    for (int rep = 0; rep < 32; ++rep) {
      const int idx = t + rep * 256;
      const int ci = idx >> 7, x = idx & 127;
      tile[x][ci] = f2bf(fm[(((size_t)(b * 256 + c0 + ci) * 128 + y) << 7) + x]);
    }
    __syncthreads();
#pragma unroll
    for (int rep = 0; rep < 4; ++rep) {
      const int idx = t + rep * 256;      // 0..1023
      const int x = idx >> 3, c8 = idx & 7;
      const ushort4 a = *(const ushort4*)&tile[x][c8 * 8];
      const ushort4 b4 = *(const ushort4*)&tile[x][c8 * 8 + 4];
      const u16x8 o = {a.x, a.y, a.z, a.w, b4.x, b4.y, b4.z, b4.w};
      *(u16x8*)(fmT + (((size_t)((b * 128 + y) * 128 + x)) << 8) + c0 + c8 * 8) = o;
    }
  } else {                                // ---- proj ----
    const int blk = (r3 / 3) * 2 + (r3 % 3) - 1;   // 0..4095
    float (*sW)[260] = (float(*)[260])&tile[0][0];       // 12*260*4 = 12480 B
    float* sb = (float*)&tile[0][0] + 12 * 260;          // +48 B  (< 17920)
    for (int i = t; i < 2048; i += 256) sW[i & 7][i >> 3] = Wo[i];
    for (int i = t; i < 1024; i += 256) sW[8 + (i & 3)][i >> 2] = Ww[i];
    if (t < 8) sb[t] = bo[t];
    else if (t < 12) sb[t] = bw[t - 8];
    __syncthreads();

    const int lane = t & 63, wv = t >> 6;
    const int ql = lane >> 4, kc = lane & 15;
    const int qi = blk * 16 + wv * 4 + ql;
    const float mf = (valid[qi] != 0) ? 1.0f : 0.0f;

    float4 qv[4];
#pragma unroll
    for (int i = 0; i < 4; ++i)
      qv[i] = *(const float4*)(queries + (size_t)qi * 256 + kc * 4 + i * 64);

    float pr[12];
#pragma unroll
    for (int j = 0; j < 12; ++j) {
      float s = 0.f;
#pragma unroll
      for (int i = 0; i < 4; ++i)
        s += dot4(qv[i], *(const float4*)&sW[j][kc * 4 + i * 64]);
      pr[j] = s;
    }
#pragma unroll
    for (int m = 1; m < 16; m <<= 1) {
#pragma unroll
      for (int j = 0; j < 12; ++j) pr[j] += __shfl_xor(pr[j], m, 64);
    }
    if (kc == 0) {
      float4* pp = (float4*)(proj + (size_t)qi * 16);
      const float4 o0 = {pr[0] + sb[0], pr[1] + sb[1], pr[2] + sb[2],  pr[3] + sb[3]};
      const float4 o1 = {pr[4] + sb[4], pr[5] + sb[5], pr[6] + sb[6],  pr[7] + sb[7]};
      const float4 o2 = {pr[8] + sb[8], pr[9] + sb[9], pr[10] + sb[10], pr[11] + sb[11]};
      pp[0] = o0; pp[1] = o1; pp[2] = o2;
    }
#pragma unroll
    for (int i = 0; i < 4; ++i) {
      ushort4 h;
      h.x = f2bf(qv[i].x * mf); h.y = f2bf(qv[i].y * mf);
      h.z = f2bf(qv[i].z * mf); h.w = f2bf(qv[i].w * mf);
      *(ushort4*)(qraw + (size_t)qi * 512 + kc * 4 + i * 64) = h;
    }
  }
}

// ---------------- 2) gather: 4 queries/wave, branchless, packed ------------
__global__ void __launch_bounds__(256) k_gather(
    const float* __restrict__ proj, const float* __restrict__ ref,
    const int* __restrict__ valid, const ushort* __restrict__ fmT,
    ushort* __restrict__ qraw, float* __restrict__ cov) {
  const int t = threadIdx.x, lane = t & 63, wv = t >> 6;
  const int qs = lane >> 4;            // query slot within wave
  const int kc = lane & 15;            // channel group (8 ch per half)
  const int xcd = blockIdx.x & 7;
  const int b = xcd >> 1;
  const int p = ((blockIdx.x >> 3) << 1) | (xcd & 1);   // 0..511 within batch
  const ushort* fmTb = fmT + ((size_t)b << 22);

#pragma unroll 1
  for (int it = 0; it < 2; ++it) {
    const int qi = b * 16384 + it * 8192 + p * 16 + wv * 4 + qs;
    const float mf = (valid[qi] != 0) ? 1.0f : 0.0f;
    const float4 pA = *(const float4*)(proj + (size_t)qi * 16);
    const float4 pB = *(const float4*)(proj + (size_t)qi * 16 + 4);
    const float4 pC = *(const float4*)(proj + (size_t)qi * 16 + 8);
    const float rx = ref[qi * 2], ry = ref[qi * 2 + 1];

    const float po[8] = {pA.x, pA.y, pA.z, pA.w, pB.x, pB.y, pB.z, pB.w};
    float o[8];
#pragma unroll
    for (int j = 0; j < 8; ++j) {
      const float x = po[j];
      const float e = __expf(2.0f * fabsf(x));
      const float th = 1.0f - 2.0f * __builtin_amdgcn_rcpf(e + 1.0f);
      o[j] = copysignf(th, x) * OFFSET_SCALE;
    }
    float wl[4] = {pC.x, pC.y, pC.z, pC.w};
    const float wmax = fmaxf(fmaxf(wl[0], wl[1]), fmaxf(wl[2], wl[3]));
    float wsum = 0.f;
#pragma unroll
    for (int j = 0; j < 4; ++j) { wl[j] = __expf(wl[j] - wmax); wsum += wl[j]; }
    const float winv = mf * __builtin_amdgcn_rcpf(wsum);

    f32x2 acc[8] = {};
    float cv = 0.f;

#define CORN(PIXPTR, CF)                                                     \
    do {                                                                     \
      const float cfv = (CF);                                                \
      const uint4 u0 = *(const uint4*)((PIXPTR) + kc * 8);                   \
      const uint4 u1 = *(const uint4*)((PIXPTR) + kc * 8 + 128);             \
      const f32x2 c2 = {cfv, cfv};                                           \
      acc[0] += c2 * up2(u0.x); acc[1] += c2 * up2(u0.y);                    \
      acc[2] += c2 * up2(u0.z); acc[3] += c2 * up2(u0.w);                    \
      acc[4] += c2 * up2(u1.x); acc[5] += c2 * up2(u1.y);                    \
      acc[6] += c2 * up2(u1.z); acc[7] += c2 * up2(u1.w);                    \
    } while (0)

#pragma unroll
    for (int s = 0; s < 4; ++s) {
      const float wgt = wl[s] * winv;
      const float gx = fminf(fmaxf(rx + o[2 * s],     -1.2f), 1.2f);
      const float gy = fminf(fmaxf(ry + o[2 * s + 1], -1.2f), 1.2f);
      const float xf = (gx + 1.0f) * 63.5f;
      const float yf = (gy + 1.0f) * 63.5f;
      const float x0f = floorf(xf), y0f = floorf(yf);
      const float wx = xf - x0f, wy = yf - y0f;
      const int x0 = (int)x0f, y0 = (int)y0f;
      const float wx0 = ((unsigned)x0 < 128u) ? (1.0f - wx) : 0.0f;
      const float wx1 = ((unsigned)(x0 + 1) < 128u) ? wx : 0.0f;
      const float wy0 = ((unsigned)y0 < 128u) ? (wgt * (1.0f - wy)) : 0.0f;
      const float wy1 = ((unsigned)(y0 + 1) < 128u) ? (wgt * wy) : 0.0f;
      const int xc0 = min(max(x0, 0), 127), xc1 = min(max(x0 + 1, 0), 127);
      const int yc0 = min(max(y0, 0), 127), yc1 = min(max(y0 + 1, 0), 127);
      cv += (wx0 + wx1) * (wy0 + wy1);
      const ushort* r0 = fmTb + ((size_t)yc0 << 15);   // yc0*128*256
      const ushort* r1 = fmTb + ((size_t)yc1 << 15);
      CORN(r0 + (xc0 << 8), wy0 * wx0);
      CORN(r0 + (xc1 << 8), wy0 * wx1);
      CORN(r1 + (xc0 << 8), wy1 * wx0);
      CORN(r1 + (xc1 << 8), wy1 * wx1);
    }
#undef CORN

    uint4 w0, w1;
    w0.x = pkbf(acc[0]); w0.y = pkbf(acc[1]); w0.z = pkbf(acc[2]); w0.w = pkbf(acc[3]);
    w1.x = pkbf(acc[4]); w1.y = pkbf(acc[5]); w1.z = pkbf(acc[6]); w1.w = pkbf(acc[7]);
    *(uint4*)(qraw + (size_t)qi * 512 + 256 + kc * 8) = w0;
    *(uint4*)(qraw + (size_t)qi * 512 + 256 + 128 + kc * 8) = w1;
    if (kc == 0) cov[qi] = cv;
  }
}

// ---------------- 3) fused GEMM1+GEMM2, M-tile 64, 4 waves -----------------
__global__ void __launch_bounds__(256, 3) k_gemm_fused(
    const ushort* __restrict__ qraw, const ushort* __restrict__ ABt,
    const ushort* __restrict__ W2t, const int* __restrict__ valid,
    const float* __restrict__ cov, const float* __restrict__ uvec,
    const float* __restrict__ vvec, const float* __restrict__ b1,
    const float* __restrict__ b2, float* __restrict__ out) {
  __shared__ ushort As[64 * 32];      // 4 KB
  __shared__ ushort Bs[256 * 32];     // 16 KB
  __shared__ ushort Hs[64 * 256];     // 32 KB, slot-XOR swizzled
  const int t = threadIdx.x;
  const int m0 = blockIdx.x * 64;
  const int wn = t >> 6, lane = t & 63;
  const int lr = lane & 15, lg = lane >> 4;

  const int srow = t >> 2;
  const int schunk = ((t & 3) ^ ((srow >> 1) & 3)) * 8;  // pre-swizzled source chunk
  const int swz = (lg ^ ((lr >> 1) & 3)) * 8;            // swizzled read offset

  const ushort* ag = qraw + (size_t)(m0 + srow) * 512 + schunk;
  const ushort* bg = ABt + (size_t)srow * 512 + schunk;
  ushort* la = As + t * 8;
  ushort* lb = Bs + t * 8;

  f32x4 acc[4][4] = {};

  // ---- phase 1: K = 512 ----
  for (int k0 = 0; k0 < 512; k0 += 32) {
    __syncthreads();
    gload16(ag + k0, la);
    gload16(bg + k0, lb);
    gload16(bg + 64 * 512 + k0, lb + 2048);
    gload16(bg + 128 * 512 + k0, lb + 4096);
    gload16(bg + 192 * 512 + k0, lb + 6144);
    __syncthreads();
    bf16x8 af[4], bfr[4];
#pragma unroll
    for (int m = 0; m < 4; ++m)
      af[m] = *(const bf16x8*)(As + (m * 16 + lr) * 32 + swz);
#pragma unroll
    for (int n = 0; n < 4; ++n)
      bfr[n] = *(const bf16x8*)(Bs + (wn * 64 + n * 16 + lr) * 32 + swz);
#pragma unroll
    for (int m = 0; m < 4; ++m)
#pragma unroll
      for (int n = 0; n < 4; ++n)
        acc[m][n] = __builtin_amdgcn_mfma_f32_16x16x32_bf16(af[m], bfr[n], acc[m][n], 0, 0, 0);
  }

  // ---- epilogue 1 -> Hs (bf16, swizzled) ----
  {
    float uu[4], vv[4], bb[4];
#pragma unroll
    for (int n = 0; n < 4; ++n) {
      const int col = wn * 64 + n * 16 + lr;
      uu[n] = uvec[col]; vv[n] = vvec[col]; bb[n] = b1[col];
    }
#pragma unroll
    for (int m = 0; m < 4; ++m)
#pragma unroll
      for (int j = 0; j < 4; ++j) {
        const int row = m * 16 + lg * 4 + j;      // local row
        const float mfv = valid[m0 + row] ? 1.0f : 0.0f;
        const float cvr = cov[m0 + row];
#pragma unroll
        for (int n = 0; n < 4; ++n) {
          const int col = wn * 64 + n * 16 + lr;
          float r = acc[m][n][j] + mfv * uu[n] + cvr * vv[n] + bb[n];
          r = fmaxf(r, 0.0f);
          const int slot = (col >> 3) ^ (row & 7);
          Hs[row * 256 + slot * 8 + (col & 7)] = f2bf(r);
        }
      }
  }

  // ---- phase 2: K = 256, A = Hs, B = W2t ----
  const ushort* cg = W2t + (size_t)srow * 256 + schunk;
#pragma unroll
  for (int m = 0; m < 4; ++m)
#pragma unroll
    for (int n = 0; n < 4; ++n) {
      f32x4 z = {0.f, 0.f, 0.f, 0.f};
      acc[m][n] = z;
    }

  for (int k0 = 0; k0 < 256; k0 += 32) {
    __syncthreads();
    gload16(cg + k0, lb);
    gload16(cg + 64 * 256 + k0, lb + 2048);
    gload16(cg + 128 * 256 + k0, lb + 4096);
    gload16(cg + 192 * 256 + k0, lb + 6144);
    __syncthreads();
    bf16x8 af[4], bfr[4];
#pragma unroll
    for (int m = 0; m < 4; ++m) {
      const int slot = ((k0 >> 3) + lg) ^ (lr & 7);
      af[m] = *(const bf16x8*)(Hs + (m * 16 + lr) * 256 + slot * 8);
    }
#pragma unroll
    for (int n = 0; n < 4; ++n)
      bfr[n] = *(const bf16x8*)(Bs + (wn * 64 + n * 16 + lr) * 32 + swz);
#pragma unroll
    for (int m = 0; m < 4; ++m)
#pragma unroll
      for (int n = 0; n < 4; ++n)
        acc[m][n] = __builtin_amdgcn_mfma_f32_16x16x32_bf16(af[m], bfr[n], acc[m][n], 0, 0, 0);
  }

  // ---- epilogue 2 -> out fp32 ----
  {
    float bb[4];
#pragma unroll
    for (int n = 0; n < 4; ++n) bb[n] = b2[wn * 64 + n * 16 + lr];
#pragma unroll
    for (int m = 0; m < 4; ++m)
#pragma unroll
      for (int j = 0; j < 4; ++j) {
        const int row = m0 + m * 16 + lg * 4 + j;
#pragma unroll
        for (int n = 0; n < 4; ++n)
          out[(size_t)row * 256 + wn * 64 + n * 16 + lr] = acc[m][n][j] + bb[n];
      }
  }
}

extern "C" void kernel_launch(void* const* d_in, const int* in_sizes, int n_in,
                              void* d_out, int out_size, void* d_ws, size_t ws_size,
                              hipStream_t stream) {
  const float* queries = (const float*)d_in[0];
  const float* ref     = (const float*)d_in[1];
  const float* fm      = (const float*)d_in[2];
  const int*   valid   = (const int*)d_in[3];
  const float* Wq = (const float*)d_in[4];
  const float* bq = (const float*)d_in[5];
  const float* Wf = (const float*)d_in[6];
  const float* bf = (const float*)d_in[7];
  const float* Wo = (const float*)d_in[8];
  const float* bo = (const float*)d_in[9];
  const float* Ww = (const float*)d_in[10];
  const float* bw = (const float*)d_in[11];
  const float* W1 = (const float*)d_in[12];
  const float* b1 = (const float*)d_in[13];
  const float* W2 = (const float*)d_in[14];
  const float* b2 = (const float*)d_in[15];
  float* out = (float*)d_out;

  // ws layout (bytes): qraw 67108864 | cov 262144 | ABt 262144 | W2t 131072 | u,v 2048
  char* ws = (char*)d_ws;
  ushort* qraw = (ushort*)ws;                         // [65536, 512] bf16
  float*  cov  = (float*)(ws + 67108864);             // [65536]
  ushort* ABt  = (ushort*)(ws + 67108864 + 262144);   // [256, 512] bf16
  ushort* W2t  = (ushort*)(ws + 67108864 + 524288);   // [256, 256] bf16
  float*  uvec = (float*)(ws + 67108864 + 655360);
  float*  vvec = uvec + 256;

  // d_out multi-duty (all regions dead before k_gemm_fused writes out):
  //   floats [0 .. 8388608)        fmT bf16 (16.77M ushorts)
  //   floats [9437184 .. 10485760) proj [65536,16] f32
  ushort* fmT  = (ushort*)d_out;
  float*  proj = out + 9437184;

  k_misc<<<6193, 256, 0, stream>>>(fm, fmT, Wq, Wf, W1, W2, bq, bf, ABt, W2t,
                                   uvec, vvec, queries, valid, Wo, bo, Ww, bw,
                                   proj, qraw);
  k_gather<<<2048, 256, 0, stream>>>(proj, ref, valid, fmT, qraw, cov);
  k_gemm_fused<<<1024, 256, 0, stream>>>(qraw, ABt, W2t, valid, cov, uvec, vvec,
                                         b1, b2, out);
}